// Round 15
// baseline (300.065 us; speedup 1.0000x reference)
//
#include <hip/hip_runtime.h>
#include <math.h>

// Sizes (fixed by the reference)
#define NB 1024
#define TT 5
#define NN 6
#define DD 192
#define EE 12
#define MM 12
#define LL 512
#define OO 6
#define GOUT 768              // GRU GEMM N: [r|z|inn|hn]
#define KPAD 224              // GRU K: 192 (h) + 12 (x) + 20 pad  [h-first order!]
#define NKT (KPAD/32)         // 7 k-tiles
#define NJT (GOUT/16)         // 48 n-tiles
#define ROWS 30               // (t,n) rows per batch
#define HP 196                // sh_h pitch (floats)

typedef __attribute__((ext_vector_type(8))) _Float16 f16x8;
typedef __attribute__((ext_vector_type(2))) _Float16 h2;
typedef __attribute__((ext_vector_type(4))) float f32x4;

__device__ __forceinline__ float dot4(float4 a, float4 b) {
  return a.x*b.x + a.y*b.y + a.z*b.z + a.w*b.w;
}
__device__ __forceinline__ unsigned short f2h(float f) {
  _Float16 h = (_Float16)f;
  unsigned short s; __builtin_memcpy(&s, &h, 2); return s;
}
__device__ __forceinline__ unsigned int pkrtz(float a, float b) {
  auto v = __builtin_amdgcn_cvt_pkrtz(a, b);
  return __builtin_bit_cast(unsigned int, v);
}
__device__ __forceinline__ float fsig(float x) {
  float e = __expf(-x);
  return __builtin_amdgcn_rcpf(1.f + e);
}
// tanh(x) = 2/(1+exp(-2x)) - 1  (sign-verified)
__device__ __forceinline__ float ftanh(float x) {
  float e = __expf(-2.f * x);
  return 2.f * __builtin_amdgcn_rcpf(1.f + e) - 1.f;
}
// 8 consecutive fp32 (16B-aligned) -> fp16x8 MFMA fragment (4x v_cvt_pkrtz)
__device__ __forceinline__ f16x8 frag8(const float* p) {
  float4 a = *(const float4*)p;
  float4 b = *(const float4*)(p + 4);
  uint4 u = make_uint4(pkrtz(a.x, a.y), pkrtz(a.z, a.w),
                       pkrtz(b.x, b.y), pkrtz(b.z, b.w));
  return __builtin_bit_cast(f16x8, u);
}

// ---------------------------------------------------------------- k_pack (GRU W, fp16)
// k-order: [h: k<192 -> Whh cols] [x: 192<=k<204 -> Wih] [pad]. Gate cols:
// r,z (c<384): both parts; inn (384<=c<576): Wih only (k>=192); hn (c>=576): Whh only.
__global__ void k_pack(const float* __restrict__ Wih, const float* __restrict__ Whh,
                       const float* __restrict__ bih, const float* __restrict__ bhh,
                       unsigned short* __restrict__ Bh, float* __restrict__ bias768)
{
  int idx = blockIdx.x * 256 + threadIdx.x;
  if (idx < GOUT) {
    int c = idx; float b;
    if (c < 384)      b = bih[c] + bhh[c];
    else if (c < 576) b = bih[c];
    else              b = bhh[c - 192];
    bias768[c] = b;
  }
  if (idx >= NJT*NKT*512) return;
  int e = idx & 7, l = (idx >> 3) & 63;
  int rem = idx >> 9, kt = rem % NKT, j = rem / NKT;
  int k = kt*32 + ((l >> 4) << 3) + e;
  int c = j*16 + (l & 15);
  float v = 0.f;
  if (k < 192) {
    if (c < 384)      v = Whh[(size_t)c*DD + k];
    else if (c < 576) v = 0.f;                       // inn: no h part
    else              v = Whh[(size_t)(c-192)*DD + k];
  } else if (k < 204) {
    if (c < 576)      v = Wih[c*MM + (k - 192)];
    else              v = 0.f;                       // hn: no x part
  }
  Bh[idx] = f2h(v);
}

// ---------------------------------------------------------------- k_pack_link (fp16)
// W1^T with b1 folded at k==12 (A supplies 1.0 there).
__global__ void k_pack_link(const float* __restrict__ w1, const float* __restrict__ b1,
                            unsigned short* __restrict__ BLh)
{
  int idx = blockIdx.x * 256 + threadIdx.x;
  if (idx >= 32*512) return;
  int e = idx & 7, l = (idx >> 3) & 63, nt = idx >> 9;
  int k = ((l >> 4) << 3) + e;
  int c = nt*16 + (l & 15);
  float v = 0.f;
  if (k < 12)       v = w1[c*EE + k];
  else if (k == 12) v = b1[c];
  BLh[idx] = f2h(v);
}

struct NH8 { float v[8]; };

// One GRU d-tile (compile-time I via macro => all nh indices static, no scratch).
// Reads OLD sh_h / sh_msum; result left in NHO (written back after barrier).
#define GRU_TILE(I, NHO)                                                        \
  {                                                                             \
    const int jR = wid*3 + (I);                                                 \
    const int jZ = 12 + wid*3 + (I);                                            \
    const int jI = 24 + wid*3 + (I);                                            \
    const int jH = 36 + wid*3 + (I);                                            \
    f32x4 aR0=(f32x4)0.f, aR1=(f32x4)0.f, aZ0=(f32x4)0.f, aZ1=(f32x4)0.f;       \
    f32x4 aI0=(f32x4)0.f, aI1=(f32x4)0.f, aH0=(f32x4)0.f, aH1=(f32x4)0.f;       \
    _Pragma("unroll")                                                           \
    for (int kt = 0; kt < NKT; ++kt) {                                          \
      f16x8 ah0, ah1;                                                           \
      if (kt < 6) {                                                             \
        ah0 = frag8(h0row + kt*32 + quad*8);                                    \
        ah1 = frag8(h1row + kt*32 + quad*8);                                    \
      } else {                                                                  \
        f16x8 zf = __builtin_bit_cast(f16x8, make_uint4(0u,0u,0u,0u));          \
        ah0 = (quad == 3) ? zf : frag8(x0row + quad*8);                         \
        ah1 = (quad == 3) ? zf : frag8(x1row + quad*8);                         \
      }                                                                         \
      f16x8 bR = *(const f16x8*)(Bh + (((size_t)(jR*NKT + kt)) << 9) + lane*8); \
      f16x8 bZ = *(const f16x8*)(Bh + (((size_t)(jZ*NKT + kt)) << 9) + lane*8); \
      aR0 = __builtin_amdgcn_mfma_f32_16x16x32_f16(ah0, bR, aR0, 0, 0, 0);      \
      aR1 = __builtin_amdgcn_mfma_f32_16x16x32_f16(ah1, bR, aR1, 0, 0, 0);      \
      aZ0 = __builtin_amdgcn_mfma_f32_16x16x32_f16(ah0, bZ, aZ0, 0, 0, 0);      \
      aZ1 = __builtin_amdgcn_mfma_f32_16x16x32_f16(ah1, bZ, aZ1, 0, 0, 0);      \
      if (kt < 6) {                                                             \
        f16x8 bH = *(const f16x8*)(Bh + (((size_t)(jH*NKT + kt)) << 9) + lane*8); \
        aH0 = __builtin_amdgcn_mfma_f32_16x16x32_f16(ah0, bH, aH0, 0, 0, 0);    \
        aH1 = __builtin_amdgcn_mfma_f32_16x16x32_f16(ah1, bH, aH1, 0, 0, 0);    \
      } else {                                                                  \
        f16x8 bI = *(const f16x8*)(Bh + (((size_t)(jI*NKT + kt)) << 9) + lane*8); \
        aI0 = __builtin_amdgcn_mfma_f32_16x16x32_f16(ah0, bI, aI0, 0, 0, 0);    \
        aI1 = __builtin_amdgcn_mfma_f32_16x16x32_f16(ah1, bI, aI1, 0, 0, 0);    \
      }                                                                         \
    }                                                                           \
    const int d = (wid*3 + (I))*16 + col;                                       \
    const float bR_ = bias768[d],       bZ_ = bias768[192 + d];                 \
    const float bI_ = bias768[384 + d], bH_ = bias768[576 + d];                 \
    _Pragma("unroll")                                                           \
    for (int q = 0; q < 4; ++q) {                                               \
      int g0 = quad*4 + q;                                                      \
      float r_ = fsig(aR0[q] + bR_);                                            \
      float z_ = fsig(aZ0[q] + bZ_);                                            \
      float n_ = ftanh(aI0[q] + bI_ + r_*(aH0[q] + bH_));                       \
      NHO.v[q] = (1.f - z_)*n_ + z_*sh_h[g0][d];                                \
      int g1 = 16 + quad*4 + q;                                                 \
      float r1_ = fsig(aR1[q] + bR_);                                           \
      float z1_ = fsig(aZ1[q] + bZ_);                                           \
      float n1_ = ftanh(aI1[q] + bI_ + r1_*(aH1[q] + bH_));                     \
      float hold1 = (g1 < ROWS) ? sh_h[g1][d] : 0.f;                            \
      NHO.v[4+q] = (1.f - z1_)*n1_ + z1_*hold1;                                 \
    }                                                                           \
  }

// ---------------------------------------------------------------- k_fused
// One WG per batch. LDS ~40.5KB -> 4 WG/CU (single clean pass of the 1024-WG
// grid). shA staging buffer ELIMINATED: link A read direct from sh_e/sh_m
// (pitch 8, b1-fold 1.0h pre-stored at slot 6); GRU A assembled in-register
// from fp32 sh_h via v_cvt_pkrtz (B repacked [h|x] so kt<6 is pure aligned h).
// New-h kept in registers (static-indexed NH8 via macro), written AFTER a
// barrier (direct reads + in-place update would race otherwise).
__global__ __launch_bounds__(256, 4)
void k_fused(const float* __restrict__ nr, const float* __restrict__ pos,
             const int* __restrict__ attmat,
             const unsigned short* __restrict__ BLh,
             const float* __restrict__ lw2, const float* __restrict__ lb2,
             const float* __restrict__ msg_Wh, const float* __restrict__ msg_We,
             const float* __restrict__ msg_b,
             const unsigned short* __restrict__ Bh, const float* __restrict__ bias768,
             const float* __restrict__ conv1_w, const float* __restrict__ conv1_b,
             const float* __restrict__ conv2_w, const float* __restrict__ conv2_b,
             float* __restrict__ out)
{
  __shared__ __align__(16) float sh_h[ROWS][HP];          // 23520 B fp32 state
  __shared__ __align__(16) unsigned int sh_e[180][8];     // 5760 B fp16x2 (+1.0h@6, 0@7)
  __shared__ __align__(16) unsigned int sh_m[180][8];     // 5760 B fp16x2 (+1.0h@6, 0@7)
  __shared__ __align__(16) float sh_mh[ROWS][MM];         // 1440 B
  __shared__ __align__(16) float sh_msum[ROWS][24];       // 2880 B ([12..23]=0 pad)
  __shared__ float sh_adj[192];                           // 768 B
  __shared__ __align__(16) unsigned int sh_we[MM][6];     // 288 B fp16x2 msg_We
  __shared__ float red[4][OO];                            // 96 B

  const int tid = threadIdx.x;
  const int b = blockIdx.x;
  const int lane = tid & 63, wid = tid >> 6;
  const int col = lane & 15, quad = lane >> 4;

  // ---- Phase 0: h, edge feats (fp16, padded), We (fp16) ----
  for (int i = tid; i < TT*DD*NN; i += 256) {
    int t = i / (DD*NN), rem = i % (DD*NN);
    int d = rem / NN, n = rem % NN;
    sh_h[t*NN + n][d] = nr[(size_t)b*TT*DD*NN + i];       // coalesced
  }
  for (int idx = tid; idx < 180*8; idx += 256) {
    int e = idx >> 3, p = idx & 7;
    unsigned int v = 0;
    if (p < 6) {
      int t = e / 36, ij = e % 36;
      int i_ = ij / NN, j_ = ij % NN;
      bool msk = (attmat[(b*TT + t)*36 + ij] == 1) && (i_ != j_);
      int srcn = (p < 3) ? i_ : j_;
      int c0   = (p < 3) ? 2*p : 2*p - 6;
      const float* pb = pos + (((size_t)(b*TT + t))*NN + srcn)*6;
      float a0 = msk ? pb[c0] : 0.f, a1 = msk ? pb[c0+1] : 0.f;
      v = pkrtz(a0, a1);
    } else if (p == 6) {
      v = 0x00003C00u;                                    // (1.0h, 0): b1-fold slot
    }
    sh_e[e][p] = v;
    if (p >= 6) sh_m[e][p] = v;                           // same padding for m rows
  }
  for (int idx = tid; idx < MM*6; idx += 256) {
    int o = idx / 6, p = idx % 6;
    sh_we[o][p] = pkrtz(msg_We[o*EE + 2*p], msg_We[o*EE + 2*p + 1]);
  }
  __syncthreads();

  for (int L = 0; L < 2; ++L) {
    // ---- link MFMA: A direct from sh_e (L0) / sh_m (L1); fused relu->w2->sigmoid ----
    {
      f16x8 am[3];
      #pragma unroll
      for (int mtl = 0; mtl < 3; ++mtl) {
        int r = (wid*3 + mtl)*16 + col; r = r > 179 ? 179 : r;   // clamp (rows 180+ unused)
        const unsigned int* src = (L == 0) ? &sh_e[r][0] : &sh_m[r][0];
        uint4 w = make_uint4(0u,0u,0u,0u);
        if (quad < 2) w = *(const uint4*)(src + quad*4);         // k 0..15 (incl 1.0h@12)
        am[mtl] = __builtin_bit_cast(f16x8, w);
      }
      float s[3][4];
      #pragma unroll
      for (int mtl = 0; mtl < 3; ++mtl)
        #pragma unroll
        for (int q = 0; q < 4; ++q) s[mtl][q] = 0.f;
      for (int nt = 0; nt < 32; ++nt) {
        f16x8 bh = *(const f16x8*)(BLh + nt*512 + lane*8);
        float w2v = lw2[nt*16 + col];
        #pragma unroll
        for (int mtl = 0; mtl < 3; ++mtl) {
          f32x4 acc = (f32x4)0.f;
          acc = __builtin_amdgcn_mfma_f32_16x16x32_f16(am[mtl], bh, acc, 0, 0, 0);
          #pragma unroll
          for (int q = 0; q < 4; ++q)
            s[mtl][q] += w2v * fmaxf(acc[q], 0.f);               // b1 folded into acc
        }
      }
      #pragma unroll
      for (int mtl = 0; mtl < 3; ++mtl)
        #pragma unroll
        for (int q = 0; q < 4; ++q) {
          float v = s[mtl][q];
          v += __shfl_xor(v, 1); v += __shfl_xor(v, 2);
          v += __shfl_xor(v, 4); v += __shfl_xor(v, 8);
          s[mtl][q] = v;
        }
      if (col == 0) {
        float b2 = lb2[0];
        #pragma unroll
        for (int mtl = 0; mtl < 3; ++mtl)
          #pragma unroll
          for (int q = 0; q < 4; ++q)
            sh_adj[wid*48 + mtl*16 + quad*4 + q] = fsig(s[mtl][q] + b2);
      }
    }
    __syncthreads();

    // ---- mh[r][o] = msg_b[o] + Wh[o,:] . h[r,:] ----
    for (int idx = tid; idx < ROWS*MM; idx += 256) {
      int r = idx / MM, o = idx % MM;
      const float4* wrow = (const float4*)(msg_Wh + (size_t)o*DD);
      const float4* hrow = (const float4*)&sh_h[r][0];
      float acc = msg_b[o];
      #pragma unroll 8
      for (int d4 = 0; d4 < DD/4; ++d4) acc += dot4(wrow[d4], hrow[d4]);
      sh_mh[r][o] = acc;
    }
    __syncthreads();

    // ---- m = adj * relu(mh_j + We.e)  (half2 me, packed store; slots<6 only) ----
    for (int idx = tid; idx < 180*6; idx += 256) {
      int e = idx / 6, op = idx % 6;
      int t = e / 36, j_ = e % 6;
      h2 a2 = {(_Float16)0.f, (_Float16)0.f};
      h2 b2 = {(_Float16)0.f, (_Float16)0.f};
      #pragma unroll
      for (int p = 0; p < 6; ++p) {
        h2 ev = __builtin_bit_cast(h2, sh_e[e][p]);
        a2 += __builtin_bit_cast(h2, sh_we[2*op][p]) * ev;
        b2 += __builtin_bit_cast(h2, sh_we[2*op+1][p]) * ev;
      }
      float me0 = (float)a2[0] + (float)a2[1];
      float me1 = (float)b2[0] + (float)b2[1];
      float mh0 = sh_mh[t*NN + j_][2*op];
      float mh1 = sh_mh[t*NN + j_][2*op+1];
      float adj = sh_adj[e];
      sh_m[e][op] = pkrtz(adj * fmaxf(mh0 + me0, 0.f),
                          adj * fmaxf(mh1 + me1, 0.f));
    }
    __syncthreads();

    // ---- msum[r][0..11] from fp16 m; [12..23] = 0 (GRU kt=6 pad) ----
    for (int idx = tid; idx < ROWS*24; idx += 256) {
      int r = idx / 24, o = idx % 24;
      float s = 0.f;
      if (o < 12) {
        int t = r / NN, i_ = r % NN;
        #pragma unroll
        for (int j = 0; j < 6; ++j) {
          h2 mv = __builtin_bit_cast(h2, sh_m[t*36 + i_*NN + j][o >> 1]);
          s += (float)mv[o & 1];
        }
      }
      sh_msum[r][o] = s;
    }
    __syncthreads();

    // ---- GRU: in-register A (frag8 from fp32 h/msum), deferred h write-back ----
    {
      const float* h0row = &sh_h[col][0];
      int r1c = col + 16; if (r1c > 29) r1c = 29;      // clamp; rows 30/31 guarded below
      const float* h1row = &sh_h[r1c][0];
      const float* x0row = &sh_msum[col][0];
      const float* x1row = &sh_msum[r1c][0];
      NH8 nh0, nh1, nh2;
      GRU_TILE(0, nh0)
      GRU_TILE(1, nh1)
      GRU_TILE(2, nh2)
      __syncthreads();   // ALL reads of old h (every wave, every tile) complete
      {
        const int d0 = (wid*3 + 0)*16 + col;
        const int d1 = (wid*3 + 1)*16 + col;
        const int d2 = (wid*3 + 2)*16 + col;
        #pragma unroll
        for (int q = 0; q < 4; ++q) {
          int g0 = quad*4 + q;
          sh_h[g0][d0] = nh0.v[q];
          sh_h[g0][d1] = nh1.v[q];
          sh_h[g0][d2] = nh2.v[q];
          int g1 = 16 + quad*4 + q;
          if (g1 < ROWS) {
            sh_h[g1][d0] = nh0.v[4+q];
            sh_h[g1][d1] = nh1.v[4+q];
            sh_h[g1][d2] = nh2.v[4+q];
          }
        }
      }
    }
    __syncthreads();
  }

  // ---- conv: h-load + index math once per element, 6 FMAs inside ----
  {
    float acco[OO];
    #pragma unroll
    for (int o = 0; o < OO; ++o) acco[o] = 0.f;
    for (int u = tid; u < DD*TT*NN; u += 256) {
      int r = u % ROWS, c = u / ROWS;
      float hv = sh_h[r][c];
      #pragma unroll
      for (int o = 0; o < OO; ++o)
        acco[o] += conv1_w[o*(DD*TT*NN) + u] * hv;
    }
    #pragma unroll
    for (int o = 0; o < OO; ++o) {
      float v = acco[o];
      v += __shfl_xor(v, 1);  v += __shfl_xor(v, 2);  v += __shfl_xor(v, 4);
      v += __shfl_xor(v, 8);  v += __shfl_xor(v, 16); v += __shfl_xor(v, 32);
      acco[o] = v;
    }
    if (lane == 0) {
      #pragma unroll
      for (int o = 0; o < OO; ++o) red[wid][o] = acco[o];
    }
    __syncthreads();
    if (tid == 0) {
      float y[OO];
      #pragma unroll
      for (int o = 0; o < OO; ++o) {
        float s = conv1_b[o] + red[0][o] + red[1][o] + red[2][o] + red[3][o];
        y[o] = fmaxf(s, 0.f);
      }
      #pragma unroll
      for (int q = 0; q < OO; ++q) {
        float s = conv2_b[q];
        #pragma unroll
        for (int o = 0; o < OO; ++o) s += conv2_w[q*OO + o] * y[o];
        out[b*OO + q] = s;
      }
    }
  }
}

// ---------------------------------------------------------------- launch
extern "C" void kernel_launch(void* const* d_in, const int* in_sizes, int n_in,
                              void* d_out, int out_size, void* d_ws, size_t ws_size,
                              hipStream_t stream) {
  const float* node_resnet = (const float*)d_in[0];
  const float* pos      = (const float*)d_in[1];
  const int*   attmat   = (const int*)  d_in[2];
  const float* link_w1  = (const float*)d_in[3];
  const float* link_b1  = (const float*)d_in[4];
  const float* link_w2  = (const float*)d_in[5];
  const float* link_b2  = (const float*)d_in[6];
  const float* msg_Wh   = (const float*)d_in[7];
  const float* msg_We   = (const float*)d_in[8];
  const float* msg_b    = (const float*)d_in[9];
  const float* gru_Wih  = (const float*)d_in[10];
  const float* gru_Whh  = (const float*)d_in[11];
  const float* gru_bih  = (const float*)d_in[12];
  const float* gru_bhh  = (const float*)d_in[13];
  const float* conv1_w  = (const float*)d_in[14];
  const float* conv1_b  = (const float*)d_in[15];
  const float* conv2_w  = (const float*)d_in[16];
  const float* conv2_b  = (const float*)d_in[17];
  float* out = (float*)d_out;

  // ws layout: bias768 | Bh(fp16) | BLh(fp16)   (~0.4 MB)
  float* bias = (float*)d_ws;
  unsigned short* Bh  = (unsigned short*)(bias + GOUT);
  unsigned short* BLh = Bh + (size_t)NJT*NKT*512;

  k_pack<<<(NJT*NKT*512 + 255)/256, 256, 0, stream>>>(gru_Wih, gru_Whh,
      gru_bih, gru_bhh, Bh, bias);
  k_pack_link<<<(32*512 + 255)/256, 256, 0, stream>>>(link_w1, link_b1, BLh);
  k_fused<<<NB, 256, 0, stream>>>(node_resnet, pos, attmat,
      BLh, link_w2, link_b2,
      msg_Wh, msg_We, msg_b,
      Bh, bias,
      conv1_w, conv1_b, conv2_w, conv2_b, out);
}

// Round 16
// 286.257 us; speedup vs baseline: 1.0482x; 1.0482x over previous
//
#include <hip/hip_runtime.h>
#include <math.h>

// Sizes (fixed by the reference)
#define NB 1024
#define TT 5
#define NN 6
#define DD 192
#define EE 12
#define MM 12
#define LL 512
#define OO 6
#define GOUT 768              // GRU GEMM N: [r|z|inn|hn]
#define KPAD 224              // GRU K: 192 (h) + 12 (x) + 20 pad  [h-first order!]
#define NKT (KPAD/32)         // 7 k-tiles
#define NJT (GOUT/16)         // 48 n-tiles
#define ROWS 30               // (t,n) rows per batch
#define HP 196                // sh_h pitch (floats)

typedef __attribute__((ext_vector_type(8))) _Float16 f16x8;
typedef __attribute__((ext_vector_type(2))) _Float16 h2;
typedef __attribute__((ext_vector_type(4))) float f32x4;

__device__ __forceinline__ float dot4(float4 a, float4 b) {
  return a.x*b.x + a.y*b.y + a.z*b.z + a.w*b.w;
}
__device__ __forceinline__ unsigned short f2h(float f) {
  _Float16 h = (_Float16)f;
  unsigned short s; __builtin_memcpy(&s, &h, 2); return s;
}
__device__ __forceinline__ unsigned int pkrtz(float a, float b) {
  auto v = __builtin_amdgcn_cvt_pkrtz(a, b);
  return __builtin_bit_cast(unsigned int, v);
}
__device__ __forceinline__ float fsig(float x) {
  float e = __expf(-x);
  return __builtin_amdgcn_rcpf(1.f + e);
}
// tanh(x) = 2/(1+exp(-2x)) - 1  (sign-verified)
__device__ __forceinline__ float ftanh(float x) {
  float e = __expf(-2.f * x);
  return 2.f * __builtin_amdgcn_rcpf(1.f + e) - 1.f;
}
// 8 consecutive fp32 (16B-aligned) -> fp16x8 MFMA fragment (4x v_cvt_pkrtz)
__device__ __forceinline__ f16x8 frag8(const float* p) {
  float4 a = *(const float4*)p;
  float4 b = *(const float4*)(p + 4);
  uint4 u = make_uint4(pkrtz(a.x, a.y), pkrtz(a.z, a.w),
                       pkrtz(b.x, b.y), pkrtz(b.z, b.w));
  return __builtin_bit_cast(f16x8, u);
}

// ---------------------------------------------------------------- k_pack (GRU W, fp16)
// k-order: [h: k<192 -> Whh cols] [x: 192<=k<204 -> Wih] [pad]. Gate cols:
// r,z (c<384): both parts; inn (384<=c<576): Wih only (k>=192); hn (c>=576): Whh only.
__global__ void k_pack(const float* __restrict__ Wih, const float* __restrict__ Whh,
                       const float* __restrict__ bih, const float* __restrict__ bhh,
                       unsigned short* __restrict__ Bh, float* __restrict__ bias768)
{
  int idx = blockIdx.x * 256 + threadIdx.x;
  if (idx < GOUT) {
    int c = idx; float b;
    if (c < 384)      b = bih[c] + bhh[c];
    else if (c < 576) b = bih[c];
    else              b = bhh[c - 192];
    bias768[c] = b;
  }
  if (idx >= NJT*NKT*512) return;
  int e = idx & 7, l = (idx >> 3) & 63;
  int rem = idx >> 9, kt = rem % NKT, j = rem / NKT;
  int k = kt*32 + ((l >> 4) << 3) + e;
  int c = j*16 + (l & 15);
  float v = 0.f;
  if (k < 192) {
    if (c < 384)      v = Whh[(size_t)c*DD + k];
    else if (c < 576) v = 0.f;                       // inn: no h part
    else              v = Whh[(size_t)(c-192)*DD + k];
  } else if (k < 204) {
    if (c < 576)      v = Wih[c*MM + (k - 192)];
    else              v = 0.f;                       // hn: no x part
  }
  Bh[idx] = f2h(v);
}

// ---------------------------------------------------------------- k_pack_link (fp16)
// W1^T with b1 folded at k==12 (A supplies 1.0 there).
__global__ void k_pack_link(const float* __restrict__ w1, const float* __restrict__ b1,
                            unsigned short* __restrict__ BLh)
{
  int idx = blockIdx.x * 256 + threadIdx.x;
  if (idx >= 32*512) return;
  int e = idx & 7, l = (idx >> 3) & 63, nt = idx >> 9;
  int k = ((l >> 4) << 3) + e;
  int c = nt*16 + (l & 15);
  float v = 0.f;
  if (k < 12)       v = w1[c*EE + k];
  else if (k == 12) v = b1[c];
  BLh[idx] = f2h(v);
}

struct NH8 { float v[8]; };

// One GRU d-tile (compile-time I via macro => all nh indices static, no scratch).
// Reads OLD sh_h / sh_msum; result left in NHO (written back after barrier).
#define GRU_TILE(I, NHO)                                                        \
  {                                                                             \
    const int jR = wid*3 + (I);                                                 \
    const int jZ = 12 + wid*3 + (I);                                            \
    const int jI = 24 + wid*3 + (I);                                            \
    const int jH = 36 + wid*3 + (I);                                            \
    f32x4 aR0=(f32x4)0.f, aR1=(f32x4)0.f, aZ0=(f32x4)0.f, aZ1=(f32x4)0.f;       \
    f32x4 aI0=(f32x4)0.f, aI1=(f32x4)0.f, aH0=(f32x4)0.f, aH1=(f32x4)0.f;       \
    _Pragma("unroll")                                                           \
    for (int kt = 0; kt < NKT; ++kt) {                                          \
      f16x8 ah0, ah1;                                                           \
      if (kt < 6) {                                                             \
        ah0 = frag8(h0row + kt*32 + quad*8);                                    \
        ah1 = frag8(h1row + kt*32 + quad*8);                                    \
      } else {                                                                  \
        f16x8 zf = __builtin_bit_cast(f16x8, make_uint4(0u,0u,0u,0u));          \
        ah0 = (quad == 3) ? zf : frag8(x0row + quad*8);                         \
        ah1 = (quad == 3) ? zf : frag8(x1row + quad*8);                         \
      }                                                                         \
      f16x8 bR = *(const f16x8*)(Bh + (((size_t)(jR*NKT + kt)) << 9) + lane*8); \
      f16x8 bZ = *(const f16x8*)(Bh + (((size_t)(jZ*NKT + kt)) << 9) + lane*8); \
      aR0 = __builtin_amdgcn_mfma_f32_16x16x32_f16(ah0, bR, aR0, 0, 0, 0);      \
      aR1 = __builtin_amdgcn_mfma_f32_16x16x32_f16(ah1, bR, aR1, 0, 0, 0);      \
      aZ0 = __builtin_amdgcn_mfma_f32_16x16x32_f16(ah0, bZ, aZ0, 0, 0, 0);      \
      aZ1 = __builtin_amdgcn_mfma_f32_16x16x32_f16(ah1, bZ, aZ1, 0, 0, 0);      \
      if (kt < 6) {                                                             \
        f16x8 bH = *(const f16x8*)(Bh + (((size_t)(jH*NKT + kt)) << 9) + lane*8); \
        aH0 = __builtin_amdgcn_mfma_f32_16x16x32_f16(ah0, bH, aH0, 0, 0, 0);    \
        aH1 = __builtin_amdgcn_mfma_f32_16x16x32_f16(ah1, bH, aH1, 0, 0, 0);    \
      } else {                                                                  \
        f16x8 bI = *(const f16x8*)(Bh + (((size_t)(jI*NKT + kt)) << 9) + lane*8); \
        aI0 = __builtin_amdgcn_mfma_f32_16x16x32_f16(ah0, bI, aI0, 0, 0, 0);    \
        aI1 = __builtin_amdgcn_mfma_f32_16x16x32_f16(ah1, bI, aI1, 0, 0, 0);    \
      }                                                                         \
    }                                                                           \
    const int d = (wid*3 + (I))*16 + col;                                       \
    const float bR_ = bias768[d],       bZ_ = bias768[192 + d];                 \
    const float bI_ = bias768[384 + d], bH_ = bias768[576 + d];                 \
    _Pragma("unroll")                                                           \
    for (int q = 0; q < 4; ++q) {                                               \
      int g0 = quad*4 + q;                                                      \
      float r_ = fsig(aR0[q] + bR_);                                            \
      float z_ = fsig(aZ0[q] + bZ_);                                            \
      float n_ = ftanh(aI0[q] + bI_ + r_*(aH0[q] + bH_));                       \
      NHO.v[q] = (1.f - z_)*n_ + z_*sh_h[g0][d];                                \
      int g1 = 16 + quad*4 + q;                                                 \
      float r1_ = fsig(aR1[q] + bR_);                                           \
      float z1_ = fsig(aZ1[q] + bZ_);                                           \
      float n1_ = ftanh(aI1[q] + bI_ + r1_*(aH1[q] + bH_));                     \
      float hold1 = (g1 < ROWS) ? sh_h[g1][d] : 0.f;                            \
      NHO.v[4+q] = (1.f - z1_)*n1_ + z1_*hold1;                                 \
    }                                                                           \
  }

// ---------------------------------------------------------------- k_fused
// One WG per batch. LDS ~40.5KB. __launch_bounds__(256,3): round-15's (256,4)
// made the allocator drop to the 64-VGPR notch (natural need ~150 -> 300MB+
// scratch spill). Cap ~170 covers the need; occupancy = min(LDS:4, VGPR:3)
// = 3 WG/CU without spill. [Pre-commit: WRITE>10MB -> revert to round-14.]
__global__ __launch_bounds__(256, 3)
void k_fused(const float* __restrict__ nr, const float* __restrict__ pos,
             const int* __restrict__ attmat,
             const unsigned short* __restrict__ BLh,
             const float* __restrict__ lw2, const float* __restrict__ lb2,
             const float* __restrict__ msg_Wh, const float* __restrict__ msg_We,
             const float* __restrict__ msg_b,
             const unsigned short* __restrict__ Bh, const float* __restrict__ bias768,
             const float* __restrict__ conv1_w, const float* __restrict__ conv1_b,
             const float* __restrict__ conv2_w, const float* __restrict__ conv2_b,
             float* __restrict__ out)
{
  __shared__ __align__(16) float sh_h[ROWS][HP];          // 23520 B fp32 state
  __shared__ __align__(16) unsigned int sh_e[180][8];     // 5760 B fp16x2 (+1.0h@6, 0@7)
  __shared__ __align__(16) unsigned int sh_m[180][8];     // 5760 B fp16x2 (+1.0h@6, 0@7)
  __shared__ __align__(16) float sh_mh[ROWS][MM];         // 1440 B
  __shared__ __align__(16) float sh_msum[ROWS][24];       // 2880 B ([12..23]=0 pad)
  __shared__ float sh_adj[192];                           // 768 B
  __shared__ __align__(16) unsigned int sh_we[MM][6];     // 288 B fp16x2 msg_We
  __shared__ float red[4][OO];                            // 96 B

  const int tid = threadIdx.x;
  const int b = blockIdx.x;
  const int lane = tid & 63, wid = tid >> 6;
  const int col = lane & 15, quad = lane >> 4;

  // ---- Phase 0: h, edge feats (fp16, padded), We (fp16) ----
  for (int i = tid; i < TT*DD*NN; i += 256) {
    int t = i / (DD*NN), rem = i % (DD*NN);
    int d = rem / NN, n = rem % NN;
    sh_h[t*NN + n][d] = nr[(size_t)b*TT*DD*NN + i];       // coalesced
  }
  for (int idx = tid; idx < 180*8; idx += 256) {
    int e = idx >> 3, p = idx & 7;
    unsigned int v = 0;
    if (p < 6) {
      int t = e / 36, ij = e % 36;
      int i_ = ij / NN, j_ = ij % NN;
      bool msk = (attmat[(b*TT + t)*36 + ij] == 1) && (i_ != j_);
      int srcn = (p < 3) ? i_ : j_;
      int c0   = (p < 3) ? 2*p : 2*p - 6;
      const float* pb = pos + (((size_t)(b*TT + t))*NN + srcn)*6;
      float a0 = msk ? pb[c0] : 0.f, a1 = msk ? pb[c0+1] : 0.f;
      v = pkrtz(a0, a1);
    } else if (p == 6) {
      v = 0x00003C00u;                                    // (1.0h, 0): b1-fold slot
    }
    sh_e[e][p] = v;
    if (p >= 6) sh_m[e][p] = v;                           // same padding for m rows
  }
  for (int idx = tid; idx < MM*6; idx += 256) {
    int o = idx / 6, p = idx % 6;
    sh_we[o][p] = pkrtz(msg_We[o*EE + 2*p], msg_We[o*EE + 2*p + 1]);
  }
  __syncthreads();

  for (int L = 0; L < 2; ++L) {
    // ---- link MFMA: A direct from sh_e (L0) / sh_m (L1); fused relu->w2->sigmoid ----
    {
      f16x8 am[3];
      #pragma unroll
      for (int mtl = 0; mtl < 3; ++mtl) {
        int r = (wid*3 + mtl)*16 + col; r = r > 179 ? 179 : r;   // clamp (rows 180+ unused)
        const unsigned int* src = (L == 0) ? &sh_e[r][0] : &sh_m[r][0];
        uint4 w = make_uint4(0u,0u,0u,0u);
        if (quad < 2) w = *(const uint4*)(src + quad*4);         // k 0..15 (incl 1.0h@12)
        am[mtl] = __builtin_bit_cast(f16x8, w);
      }
      float s[3][4];
      #pragma unroll
      for (int mtl = 0; mtl < 3; ++mtl)
        #pragma unroll
        for (int q = 0; q < 4; ++q) s[mtl][q] = 0.f;
      for (int nt = 0; nt < 32; ++nt) {
        f16x8 bh = *(const f16x8*)(BLh + nt*512 + lane*8);
        float w2v = lw2[nt*16 + col];
        #pragma unroll
        for (int mtl = 0; mtl < 3; ++mtl) {
          f32x4 acc = (f32x4)0.f;
          acc = __builtin_amdgcn_mfma_f32_16x16x32_f16(am[mtl], bh, acc, 0, 0, 0);
          #pragma unroll
          for (int q = 0; q < 4; ++q)
            s[mtl][q] += w2v * fmaxf(acc[q], 0.f);               // b1 folded into acc
        }
      }
      #pragma unroll
      for (int mtl = 0; mtl < 3; ++mtl)
        #pragma unroll
        for (int q = 0; q < 4; ++q) {
          float v = s[mtl][q];
          v += __shfl_xor(v, 1); v += __shfl_xor(v, 2);
          v += __shfl_xor(v, 4); v += __shfl_xor(v, 8);
          s[mtl][q] = v;
        }
      if (col == 0) {
        float b2 = lb2[0];
        #pragma unroll
        for (int mtl = 0; mtl < 3; ++mtl)
          #pragma unroll
          for (int q = 0; q < 4; ++q)
            sh_adj[wid*48 + mtl*16 + quad*4 + q] = fsig(s[mtl][q] + b2);
      }
    }
    __syncthreads();

    // ---- mh[r][o] = msg_b[o] + Wh[o,:] . h[r,:] ----
    for (int idx = tid; idx < ROWS*MM; idx += 256) {
      int r = idx / MM, o = idx % MM;
      const float4* wrow = (const float4*)(msg_Wh + (size_t)o*DD);
      const float4* hrow = (const float4*)&sh_h[r][0];
      float acc = msg_b[o];
      #pragma unroll 8
      for (int d4 = 0; d4 < DD/4; ++d4) acc += dot4(wrow[d4], hrow[d4]);
      sh_mh[r][o] = acc;
    }
    __syncthreads();

    // ---- m = adj * relu(mh_j + We.e)  (half2 me, packed store; slots<6 only) ----
    for (int idx = tid; idx < 180*6; idx += 256) {
      int e = idx / 6, op = idx % 6;
      int t = e / 36, j_ = e % 6;
      h2 a2 = {(_Float16)0.f, (_Float16)0.f};
      h2 b2 = {(_Float16)0.f, (_Float16)0.f};
      #pragma unroll
      for (int p = 0; p < 6; ++p) {
        h2 ev = __builtin_bit_cast(h2, sh_e[e][p]);
        a2 += __builtin_bit_cast(h2, sh_we[2*op][p]) * ev;
        b2 += __builtin_bit_cast(h2, sh_we[2*op+1][p]) * ev;
      }
      float me0 = (float)a2[0] + (float)a2[1];
      float me1 = (float)b2[0] + (float)b2[1];
      float mh0 = sh_mh[t*NN + j_][2*op];
      float mh1 = sh_mh[t*NN + j_][2*op+1];
      float adj = sh_adj[e];
      sh_m[e][op] = pkrtz(adj * fmaxf(mh0 + me0, 0.f),
                          adj * fmaxf(mh1 + me1, 0.f));
    }
    __syncthreads();

    // ---- msum[r][0..11] from fp16 m; [12..23] = 0 (GRU kt=6 pad) ----
    for (int idx = tid; idx < ROWS*24; idx += 256) {
      int r = idx / 24, o = idx % 24;
      float s = 0.f;
      if (o < 12) {
        int t = r / NN, i_ = r % NN;
        #pragma unroll
        for (int j = 0; j < 6; ++j) {
          h2 mv = __builtin_bit_cast(h2, sh_m[t*36 + i_*NN + j][o >> 1]);
          s += (float)mv[o & 1];
        }
      }
      sh_msum[r][o] = s;
    }
    __syncthreads();

    // ---- GRU: in-register A (frag8 from fp32 h/msum), deferred h write-back ----
    {
      const float* h0row = &sh_h[col][0];
      int r1c = col + 16; if (r1c > 29) r1c = 29;      // clamp; rows 30/31 guarded below
      const float* h1row = &sh_h[r1c][0];
      const float* x0row = &sh_msum[col][0];
      const float* x1row = &sh_msum[r1c][0];
      NH8 nh0, nh1, nh2;
      GRU_TILE(0, nh0)
      GRU_TILE(1, nh1)
      GRU_TILE(2, nh2)
      __syncthreads();   // ALL reads of old h (every wave, every tile) complete
      {
        const int d0 = (wid*3 + 0)*16 + col;
        const int d1 = (wid*3 + 1)*16 + col;
        const int d2 = (wid*3 + 2)*16 + col;
        #pragma unroll
        for (int q = 0; q < 4; ++q) {
          int g0 = quad*4 + q;
          sh_h[g0][d0] = nh0.v[q];
          sh_h[g0][d1] = nh1.v[q];
          sh_h[g0][d2] = nh2.v[q];
          int g1 = 16 + quad*4 + q;
          if (g1 < ROWS) {
            sh_h[g1][d0] = nh0.v[4+q];
            sh_h[g1][d1] = nh1.v[4+q];
            sh_h[g1][d2] = nh2.v[4+q];
          }
        }
      }
    }
    __syncthreads();
  }

  // ---- conv: h-load + index math once per element, 6 FMAs inside ----
  {
    float acco[OO];
    #pragma unroll
    for (int o = 0; o < OO; ++o) acco[o] = 0.f;
    for (int u = tid; u < DD*TT*NN; u += 256) {
      int r = u % ROWS, c = u / ROWS;
      float hv = sh_h[r][c];
      #pragma unroll
      for (int o = 0; o < OO; ++o)
        acco[o] += conv1_w[o*(DD*TT*NN) + u] * hv;
    }
    #pragma unroll
    for (int o = 0; o < OO; ++o) {
      float v = acco[o];
      v += __shfl_xor(v, 1);  v += __shfl_xor(v, 2);  v += __shfl_xor(v, 4);
      v += __shfl_xor(v, 8);  v += __shfl_xor(v, 16); v += __shfl_xor(v, 32);
      acco[o] = v;
    }
    if (lane == 0) {
      #pragma unroll
      for (int o = 0; o < OO; ++o) red[wid][o] = acco[o];
    }
    __syncthreads();
    if (tid == 0) {
      float y[OO];
      #pragma unroll
      for (int o = 0; o < OO; ++o) {
        float s = conv1_b[o] + red[0][o] + red[1][o] + red[2][o] + red[3][o];
        y[o] = fmaxf(s, 0.f);
      }
      #pragma unroll
      for (int q = 0; q < OO; ++q) {
        float s = conv2_b[q];
        #pragma unroll
        for (int o = 0; o < OO; ++o) s += conv2_w[q*OO + o] * y[o];
        out[b*OO + q] = s;
      }
    }
  }
}

// ---------------------------------------------------------------- launch
extern "C" void kernel_launch(void* const* d_in, const int* in_sizes, int n_in,
                              void* d_out, int out_size, void* d_ws, size_t ws_size,
                              hipStream_t stream) {
  const float* node_resnet = (const float*)d_in[0];
  const float* pos      = (const float*)d_in[1];
  const int*   attmat   = (const int*)  d_in[2];
  const float* link_w1  = (const float*)d_in[3];
  const float* link_b1  = (const float*)d_in[4];
  const float* link_w2  = (const float*)d_in[5];
  const float* link_b2  = (const float*)d_in[6];
  const float* msg_Wh   = (const float*)d_in[7];
  const float* msg_We   = (const float*)d_in[8];
  const float* msg_b    = (const float*)d_in[9];
  const float* gru_Wih  = (const float*)d_in[10];
  const float* gru_Whh  = (const float*)d_in[11];
  const float* gru_bih  = (const float*)d_in[12];
  const float* gru_bhh  = (const float*)d_in[13];
  const float* conv1_w  = (const float*)d_in[14];
  const float* conv1_b  = (const float*)d_in[15];
  const float* conv2_w  = (const float*)d_in[16];
  const float* conv2_b  = (const float*)d_in[17];
  float* out = (float*)d_out;

  // ws layout: bias768 | Bh(fp16) | BLh(fp16)   (~0.4 MB)
  float* bias = (float*)d_ws;
  unsigned short* Bh  = (unsigned short*)(bias + GOUT);
  unsigned short* BLh = Bh + (size_t)NJT*NKT*512;

  k_pack<<<(NJT*NKT*512 + 255)/256, 256, 0, stream>>>(gru_Wih, gru_Whh,
      gru_bih, gru_bhh, Bh, bias);
  k_pack_link<<<(32*512 + 255)/256, 256, 0, stream>>>(link_w1, link_b1, BLh);
  k_fused<<<NB, 256, 0, stream>>>(node_resnet, pos, attmat,
      BLh, link_w2, link_b2,
      msg_Wh, msg_We, msg_b,
      Bh, bias,
      conv1_w, conv1_b, conv2_w, conv2_b, out);
}

// Round 17
// 142.047 us; speedup vs baseline: 2.1124x; 2.0152x over previous
//
#include <hip/hip_runtime.h>
#include <math.h>

// Sizes (fixed by the reference)
#define NB 1024
#define TT 5
#define NN 6
#define DD 192
#define EE 12
#define MM 12
#define LL 512
#define OO 6
#define GOUT 768              // GRU GEMM N: [r|z|inn|hn]
#define KPAD 224              // GRU K: 12 (x) + 192 (h) + 20 pad
#define NKT (KPAD/32)         // 7 k-tiles
#define NJT (GOUT/16)         // 48 n-tiles
#define ROWS 30               // (t,n) rows per batch
#define HP 196                // sh_h pitch (floats)
#define GRUPU 116             // gruA pitch (uints) = 464 B (2-way bank alias only)

typedef __attribute__((ext_vector_type(8))) _Float16 f16x8;
typedef __attribute__((ext_vector_type(2))) _Float16 h2;
typedef __attribute__((ext_vector_type(4))) float f32x4;

__device__ __forceinline__ float dot4(float4 a, float4 b) {
  return a.x*b.x + a.y*b.y + a.z*b.z + a.w*b.w;
}
__device__ __forceinline__ unsigned short f2h(float f) {
  _Float16 h = (_Float16)f;
  unsigned short s; __builtin_memcpy(&s, &h, 2); return s;
}
__device__ __forceinline__ float h2f(unsigned short s) {
  _Float16 h; __builtin_memcpy(&h, &s, 2); return (float)h;
}
// pack two f32 -> fp16x2 in ONE instruction (v_cvt_pkrtz_f16_f32)
__device__ __forceinline__ unsigned int pkrtz(float a, float b) {
  auto v = __builtin_amdgcn_cvt_pkrtz(a, b);
  return __builtin_bit_cast(unsigned int, v);
}
__device__ __forceinline__ float fsig(float x) {
  float e = __expf(-x);
  return __builtin_amdgcn_rcpf(1.f + e);
}
// tanh(x) = 2/(1+exp(-2x)) - 1  (sign-verified)
__device__ __forceinline__ float ftanh(float x) {
  float e = __expf(-2.f * x);
  return 2.f * __builtin_amdgcn_rcpf(1.f + e) - 1.f;
}

// ---------------------------------------------------------------- k_pack (GRU W, fp16)
// r14 k-order: [x: k<12 -> Wih] [h: 12<=k<204 -> Whh] [pad].
// r,z (c<384): both; inn (384<=c<576): Wih only (k<12); hn (c>=576): Whh only.
__global__ void k_pack(const float* __restrict__ Wih, const float* __restrict__ Whh,
                       const float* __restrict__ bih, const float* __restrict__ bhh,
                       unsigned short* __restrict__ Bh, float* __restrict__ bias768)
{
  int idx = blockIdx.x * 256 + threadIdx.x;
  if (idx < GOUT) {
    int c = idx; float b;
    if (c < 384)      b = bih[c] + bhh[c];
    else if (c < 576) b = bih[c];
    else              b = bhh[c - 192];
    bias768[c] = b;
  }
  if (idx >= NJT*NKT*512) return;
  int e = idx & 7, l = (idx >> 3) & 63;
  int rem = idx >> 9, kt = rem % NKT, j = rem / NKT;
  int k = kt*32 + ((l >> 4) << 3) + e;
  int c = j*16 + (l & 15);
  float v = 0.f;
  if (k < 204) {
    if (c < 384)      v = (k < 12) ? Wih[c*MM + k] : Whh[(size_t)c*DD + (k-12)];
    else if (c < 576) v = (k < 12) ? Wih[c*MM + k] : 0.f;
    else              v = (k < 12) ? 0.f : Whh[(size_t)(c-192)*DD + (k-12)];
  }
  Bh[idx] = f2h(v);
}

// ---------------------------------------------------------------- k_pack_link (fp16)
// W1^T only (k<12); b1 is added post-MFMA from global in k_fused.
__global__ void k_pack_link(const float* __restrict__ w1,
                            unsigned short* __restrict__ BLh)
{
  int idx = blockIdx.x * 256 + threadIdx.x;
  if (idx >= 32*512) return;
  int e = idx & 7, l = (idx >> 3) & 63, nt = idx >> 9;
  int k = ((l >> 4) << 3) + e;
  int c = nt*16 + (l & 15);
  BLh[idx] = f2h((k < 12) ? w1[c*EE + k] : 0.f);
}

// ---------------------------------------------------------------- k_fused
// One WG per batch. LDS 40,952 B -> EXACTLY 4 WG/CU (4x40960 = 160KB).
// vs r14 (52.2KB, 3/CU): linkA staging eliminated (direct quad-split reads
// from pitch-6 sh_e/sh_m), GRU A staged in two 16-row halves (rows are
// independent in the GRU), mh/adj stored fp16, red aliased onto dead sh_mh.
// __launch_bounds__(256,2): empirical allocator law cap=256/arg; arg>=3
// spills this family (r9-12: 84 regs/212MB, r15: 64/600MB, r16: 84/500MB).
__global__ __launch_bounds__(256, 2)
void k_fused(const float* __restrict__ nr, const float* __restrict__ pos,
             const int* __restrict__ attmat,
             const unsigned short* __restrict__ BLh,
             const float* __restrict__ lb1, const float* __restrict__ lw2,
             const float* __restrict__ lb2,
             const float* __restrict__ msg_Wh, const float* __restrict__ msg_We,
             const float* __restrict__ msg_b,
             const unsigned short* __restrict__ Bh, const float* __restrict__ bias768,
             const float* __restrict__ conv1_w, const float* __restrict__ conv1_b,
             const float* __restrict__ conv2_w, const float* __restrict__ conv2_b,
             float* __restrict__ out)
{
  __shared__ __align__(16) float sh_h[ROWS][HP];          // 23520 B fp32 state
  __shared__ __align__(16) unsigned int sh_e[180][6];     // 4320 B fp16x2 edge feats
  __shared__ __align__(16) unsigned int sh_m[180][6];     // 4320 B fp16x2 messages
  __shared__ __align__(16) unsigned int shA[16*GRUPU];    // 7424 B GRU A half-tile
  __shared__ __align__(16) unsigned short sh_mh[ROWS][MM];// 720 B fp16 mh
  __shared__ __align__(16) unsigned int sh_we[MM][6];     // 288 B fp16x2 msg_We
  __shared__ unsigned short sh_adj[180];                  // 360 B fp16 adj
  // total 40952 B <= 40960; red aliased onto sh_mh (dead at conv time)

  const int tid = threadIdx.x;
  const int b = blockIdx.x;
  const int lane = tid & 63, wid = tid >> 6;
  const int col = lane & 15, quad = lane >> 4;

  // ---- Phase 0: h, edge feats (fp16), We (fp16) ----
  for (int i = tid; i < TT*DD*NN; i += 256) {
    int t = i / (DD*NN), rem = i % (DD*NN);
    int d = rem / NN, n = rem % NN;
    sh_h[t*NN + n][d] = nr[(size_t)b*TT*DD*NN + i];       // coalesced
  }
  for (int idx = tid; idx < 180*6; idx += 256) {
    int e = idx / 6, p = idx % 6;
    int t = e / 36, ij = e % 36;
    int i_ = ij / NN, j_ = ij % NN;
    bool msk = (attmat[(b*TT + t)*36 + ij] == 1) && (i_ != j_);
    int srcn = (p < 3) ? i_ : j_;
    int c0   = (p < 3) ? 2*p : 2*p - 6;
    const float* pb = pos + (((size_t)(b*TT + t))*NN + srcn)*6;
    float a0 = msk ? pb[c0] : 0.f, a1 = msk ? pb[c0+1] : 0.f;
    sh_e[e][p] = pkrtz(a0, a1);
  }
  for (int idx = tid; idx < MM*6; idx += 256) {
    int o = idx / 6, p = idx % 6;
    sh_we[o][p] = pkrtz(msg_We[o*EE + 2*p], msg_We[o*EE + 2*p + 1]);
  }
  __syncthreads();

  for (int L = 0; L < 2; ++L) {
    // ---- link MFMA: A direct from sh_e/sh_m (pitch 6 uints = 24B rows).
    // A-k = quad*8+e: quad0 = uints 0..3, quad1 = uints 4,5 + zeros, quad>=2 = 0.
    {
      f16x8 am[3];
      #pragma unroll
      for (int mtl = 0; mtl < 3; ++mtl) {
        int r = (wid*3 + mtl)*16 + col; r = r > 179 ? 179 : r;  // rows 180+ unused
        const unsigned int* src = (L == 0) ? &sh_e[r][0] : &sh_m[r][0];
        uint4 w = make_uint4(0u, 0u, 0u, 0u);
        if (quad == 0) {
          uint2 lo = *(const uint2*)(src);        // 8B-aligned (24B pitch)
          uint2 hi = *(const uint2*)(src + 2);
          w = make_uint4(lo.x, lo.y, hi.x, hi.y);
        } else if (quad == 1) {
          uint2 lo = *(const uint2*)(src + 4);
          w = make_uint4(lo.x, lo.y, 0u, 0u);
        }
        am[mtl] = __builtin_bit_cast(f16x8, w);
      }
      float s[3][4];
      #pragma unroll
      for (int mtl = 0; mtl < 3; ++mtl)
        #pragma unroll
        for (int q = 0; q < 4; ++q) s[mtl][q] = 0.f;
      for (int nt = 0; nt < 32; ++nt) {
        f16x8 bh = *(const f16x8*)(BLh + nt*512 + lane*8);
        float b1v = lb1[nt*16 + col];
        float w2v = lw2[nt*16 + col];
        #pragma unroll
        for (int mtl = 0; mtl < 3; ++mtl) {
          f32x4 acc = (f32x4)0.f;
          acc = __builtin_amdgcn_mfma_f32_16x16x32_f16(am[mtl], bh, acc, 0, 0, 0);
          #pragma unroll
          for (int q = 0; q < 4; ++q)
            s[mtl][q] += w2v * fmaxf(acc[q] + b1v, 0.f);
        }
      }
      #pragma unroll
      for (int mtl = 0; mtl < 3; ++mtl)
        #pragma unroll
        for (int q = 0; q < 4; ++q) {
          float v = s[mtl][q];
          v += __shfl_xor(v, 1); v += __shfl_xor(v, 2);
          v += __shfl_xor(v, 4); v += __shfl_xor(v, 8);
          s[mtl][q] = v;
        }
      if (col == 0) {
        float b2 = lb2[0];
        #pragma unroll
        for (int mtl = 0; mtl < 3; ++mtl)
          #pragma unroll
          for (int q = 0; q < 4; ++q) {
            int e = wid*48 + mtl*16 + quad*4 + q;
            if (e < 180) sh_adj[e] = f2h(fsig(s[mtl][q] + b2));
          }
      }
    }
    __syncthreads();

    // ---- mh[r][o] = msg_b[o] + Wh[o,:] . h[r,:]  (fp16 store) ----
    for (int idx = tid; idx < ROWS*MM; idx += 256) {
      int r = idx / MM, o = idx % MM;
      const float4* wrow = (const float4*)(msg_Wh + (size_t)o*DD);
      const float4* hrow = (const float4*)&sh_h[r][0];
      float acc = msg_b[o];
      #pragma unroll 8
      for (int d4 = 0; d4 < DD/4; ++d4) acc += dot4(wrow[d4], hrow[d4]);
      sh_mh[r][o] = f2h(acc);
    }
    __syncthreads();

    // ---- m = adj * relu(mh_j + We.e)  (half2 me, packed store) ----
    for (int idx = tid; idx < 180*6; idx += 256) {
      int e = idx / 6, op = idx % 6;
      int t = e / 36, j_ = e % 6;
      h2 a2 = {(_Float16)0.f, (_Float16)0.f};
      h2 b2 = {(_Float16)0.f, (_Float16)0.f};
      #pragma unroll
      for (int p = 0; p < 6; ++p) {
        h2 ev = __builtin_bit_cast(h2, sh_e[e][p]);
        a2 += __builtin_bit_cast(h2, sh_we[2*op][p]) * ev;
        b2 += __builtin_bit_cast(h2, sh_we[2*op+1][p]) * ev;
      }
      float me0 = (float)a2[0] + (float)a2[1];
      float me1 = (float)b2[0] + (float)b2[1];
      float mh0 = h2f(sh_mh[t*NN + j_][2*op]);
      float mh1 = h2f(sh_mh[t*NN + j_][2*op + 1]);
      float adj = h2f(sh_adj[e]);
      sh_m[e][op] = pkrtz(adj * fmaxf(mh0 + me0, 0.f),
                          adj * fmaxf(mh1 + me1, 0.f));
    }
    __syncthreads();

    // ---- GRU in two 16-row halves (rows independent: row r needs only
    //      x_r | h_r). Per half: stage A (msum inline, h fp32->fp16) ->
    //      barrier -> MFMA + gate epilogue writes sh_h rows of this half. ----
    #pragma unroll 1
    for (int H = 0; H < 2; ++H) {
      for (int idx = tid; idx < 16*(KPAD/2); idx += 256) {
        int r = idx / (KPAD/2), kp = idx % (KPAD/2);
        int grow = H*16 + r;
        unsigned int v = 0;
        if (grow < ROWS) {
          if (kp < 6) {          // x part: msum over 6 source nodes
            int t = grow / NN, i_ = grow % NN;
            const unsigned int* mrow = &sh_m[t*36 + i_*NN][kp];
            float a0 = 0.f, a1 = 0.f;
            #pragma unroll
            for (int j = 0; j < 6; ++j) {
              h2 mv = __builtin_bit_cast(h2, mrow[j*6]);
              a0 += (float)mv[0]; a1 += (float)mv[1];
            }
            v = pkrtz(a0, a1);
          } else if (kp < 102) { // h part
            float2 hv = *(const float2*)&sh_h[grow][2*kp - 12];
            v = pkrtz(hv.x, hv.y);
          }
        }
        shA[r*GRUPU + kp] = v;
      }
      __syncthreads();

      {
        const char* ahb = (const char*)shA + col*(GRUPU*4) + quad*16;
        #pragma unroll 1
        for (int i = 0; i < 3; ++i) {
          const int jR = wid*3 + i;
          const int jZ = 12 + wid*3 + i;
          const int jI = 24 + wid*3 + i;
          const int jH = 36 + wid*3 + i;
          f32x4 aR = (f32x4)0.f, aZ = (f32x4)0.f;
          f32x4 aI = (f32x4)0.f, aH = (f32x4)0.f;
          #pragma unroll
          for (int kt = 0; kt < NKT; ++kt) {
            f16x8 ah = *(const f16x8*)(ahb + kt*64);
            f16x8 bR = *(const f16x8*)(Bh + (((size_t)(jR*NKT + kt)) << 9) + lane*8);
            f16x8 bZ = *(const f16x8*)(Bh + (((size_t)(jZ*NKT + kt)) << 9) + lane*8);
            f16x8 bH = *(const f16x8*)(Bh + (((size_t)(jH*NKT + kt)) << 9) + lane*8);
            aR = __builtin_amdgcn_mfma_f32_16x16x32_f16(ah, bR, aR, 0, 0, 0);
            aZ = __builtin_amdgcn_mfma_f32_16x16x32_f16(ah, bZ, aZ, 0, 0, 0);
            aH = __builtin_amdgcn_mfma_f32_16x16x32_f16(ah, bH, aH, 0, 0, 0);
            if (kt == 0) {
              f16x8 bI = *(const f16x8*)(Bh + (((size_t)(jI*NKT)) << 9) + lane*8);
              aI = __builtin_amdgcn_mfma_f32_16x16x32_f16(ah, bI, aI, 0, 0, 0);
            }
          }
          const int d = (wid*3 + i)*16 + col;
          const float bR_ = bias768[d],       bZ_ = bias768[192 + d];
          const float bI_ = bias768[384 + d], bH_ = bias768[576 + d];
          #pragma unroll
          for (int q = 0; q < 4; ++q) {
            const int grow = H*16 + quad*4 + q;
            if (grow < ROWS) {
              float r_ = fsig(aR[q] + bR_);
              float z_ = fsig(aZ[q] + bZ_);
              float n_ = ftanh(aI[q] + bI_ + r_*(aH[q] + bH_));
              float hold = sh_h[grow][d];     // each (row,d) owned by 1 thread
              sh_h[grow][d] = (1.f - z_)*n_ + z_*hold;
            }
          }
        }
      }
      __syncthreads();
    }
  }

  // ---- conv: h-load + index math once per element, 6 FMAs inside ----
  {
    float* red = (float*)&sh_mh[0][0];   // sh_mh dead; 96 B needed
    float acco[OO];
    #pragma unroll
    for (int o = 0; o < OO; ++o) acco[o] = 0.f;
    for (int u = tid; u < DD*TT*NN; u += 256) {
      int r = u % ROWS, c = u / ROWS;
      float hv = sh_h[r][c];
      #pragma unroll
      for (int o = 0; o < OO; ++o)
        acco[o] += conv1_w[o*(DD*TT*NN) + u] * hv;
    }
    #pragma unroll
    for (int o = 0; o < OO; ++o) {
      float v = acco[o];
      v += __shfl_xor(v, 1);  v += __shfl_xor(v, 2);  v += __shfl_xor(v, 4);
      v += __shfl_xor(v, 8);  v += __shfl_xor(v, 16); v += __shfl_xor(v, 32);
      acco[o] = v;
    }
    __syncthreads();   // ensure sh_mh truly dead before aliasing
    if (lane == 0) {
      #pragma unroll
      for (int o = 0; o < OO; ++o) red[wid*OO + o] = acco[o];
    }
    __syncthreads();
    if (tid == 0) {
      float y[OO];
      #pragma unroll
      for (int o = 0; o < OO; ++o) {
        float s = conv1_b[o] + red[0*OO+o] + red[1*OO+o] + red[2*OO+o] + red[3*OO+o];
        y[o] = fmaxf(s, 0.f);
      }
      #pragma unroll
      for (int q = 0; q < OO; ++q) {
        float s = conv2_b[q];
        #pragma unroll
        for (int o = 0; o < OO; ++o) s += conv2_w[q*OO + o] * y[o];
        out[b*OO + q] = s;
      }
    }
  }
}

// ---------------------------------------------------------------- launch
extern "C" void kernel_launch(void* const* d_in, const int* in_sizes, int n_in,
                              void* d_out, int out_size, void* d_ws, size_t ws_size,
                              hipStream_t stream) {
  const float* node_resnet = (const float*)d_in[0];
  const float* pos      = (const float*)d_in[1];
  const int*   attmat   = (const int*)  d_in[2];
  const float* link_w1  = (const float*)d_in[3];
  const float* link_b1  = (const float*)d_in[4];
  const float* link_w2  = (const float*)d_in[5];
  const float* link_b2  = (const float*)d_in[6];
  const float* msg_Wh   = (const float*)d_in[7];
  const float* msg_We   = (const float*)d_in[8];
  const float* msg_b    = (const float*)d_in[9];
  const float* gru_Wih  = (const float*)d_in[10];
  const float* gru_Whh  = (const float*)d_in[11];
  const float* gru_bih  = (const float*)d_in[12];
  const float* gru_bhh  = (const float*)d_in[13];
  const float* conv1_w  = (const float*)d_in[14];
  const float* conv1_b  = (const float*)d_in[15];
  const float* conv2_w  = (const float*)d_in[16];
  const float* conv2_b  = (const float*)d_in[17];
  float* out = (float*)d_out;

  // ws layout: bias768 | Bh(fp16) | BLh(fp16)   (~0.4 MB)
  float* bias = (float*)d_ws;
  unsigned short* Bh  = (unsigned short*)(bias + GOUT);
  unsigned short* BLh = Bh + (size_t)NJT*NKT*512;

  k_pack<<<(NJT*NKT*512 + 255)/256, 256, 0, stream>>>(gru_Wih, gru_Whh,
      gru_bih, gru_bhh, Bh, bias);
  k_pack_link<<<(32*512 + 255)/256, 256, 0, stream>>>(link_w1, BLh);
  k_fused<<<NB, 256, 0, stream>>>(node_resnet, pos, attmat,
      BLh, link_b1, link_w2, link_b2,
      msg_Wh, msg_We, msg_b,
      Bh, bias,
      conv1_w, conv1_b, conv2_w, conv2_b, out);
}